// Round 5
// baseline (1454.458 us; speedup 1.0000x reference)
//
#include <hip/hip_runtime.h>
#include <cstddef>

// VGG-16 fwd, batch=1. R7: single persistent uber-kernel for wt+conv1+L2..L13.
//  - 512 blocks, 2 blocks/CU (LDS 80,896B <= 81,920), fully co-resident
//  - R4-proven grid barrier (monotone counter, fence release/acquire, AGENT spin)
//  - conv bodies verbatim from R6 (gl_lds dwordx4 staging, dbuf, counted vmcnt)
//  - layers with smaller grids idle extra blocks at the barrier
//  - dispatches 17 -> 5 (memset, uber, 3x gemv)
//  - FC: fp32 GEMV, weight-BW-bound (~100us floor)

typedef __attribute__((ext_vector_type(8))) short short8;
typedef __attribute__((ext_vector_type(4))) float f32x4;

__device__ inline unsigned short f2bf(float f) {
    unsigned int u = __builtin_bit_cast(unsigned int, f);
    u += 0x7FFF + ((u >> 16) & 1);          // RNE
    return (unsigned short)(u >> 16);
}

// direct global->LDS 16B: LDS dest = M0 + lane*16 (wave-uniform base in m0)
__device__ __forceinline__ void gl_lds16(const void* src, unsigned m0v) {
    asm volatile("s_mov_b32 m0, %1\n\t"
                 "global_load_lds_dwordx4 %0, off"
                 :: "v"(src), "s"(m0v) : "memory");
}

// ---------------- grid barrier (persistent kernel, all blocks co-resident) ----
__device__ __forceinline__ void gridbar(unsigned* cnt, unsigned& gen, unsigned nblk)
{
    __syncthreads();                       // drains each wave's vmem
    if (threadIdx.x == 0) {
        gen += nblk;
        __threadfence();                   // release: wb L2 device scope
        __hip_atomic_fetch_add(cnt, 1u, __ATOMIC_RELAXED, __HIP_MEMORY_SCOPE_AGENT);
        while (__hip_atomic_load(cnt, __ATOMIC_RELAXED, __HIP_MEMORY_SCOPE_AGENT) < gen)
            __builtin_amdgcn_s_sleep(8);
        __threadfence();                   // acquire: inv caches
    }
    __syncthreads();
}

// ---------------- weight transform body: OIHW fp32 -> [pos][co][ci] bf16 ----
struct WtDesc { const float* src; unsigned dst; int cin; int cout; int blk0; };
struct WtArgs { WtDesc d[12]; };

__device__ void wt_body(const WtDesc& D, int relvb, unsigned short* __restrict__ wt,
                        char* smem, int tid)
{
    unsigned short* lds = (unsigned short*)smem + (tid >> 6) * 4680;  // 9*520 per wave
    const int wv = tid >> 6, lane = tid & 63;
    const int co = relvb * 4 + wv;
    const int n = D.cin * 9;
    const int cinP = D.cin + 8;

    const float4* src = (const float4*)(D.src + (size_t)co * n);
    for (int i = lane; i < (n >> 2); i += 64) {
        float4 v = src[i];
        unsigned short b[4] = {f2bf(v.x), f2bf(v.y), f2bf(v.z), f2bf(v.w)};
        const int f0 = i * 4;
#pragma unroll
        for (int k = 0; k < 4; ++k) {
            const int f = f0 + k, ci = f / 9, pos = f - ci * 9;
            lds[pos * cinP + ci] = b[k];
        }
    }
    __syncthreads();
    unsigned short* dstb = wt + D.dst;
#pragma unroll 1
    for (int pos = 0; pos < 9; ++pos) {
        unsigned short* drow = dstb + ((size_t)pos * D.cout + co) * D.cin;
        for (int c4 = lane; c4 < (D.cin >> 2); c4 += 64) {
            ushort4 u = *(const ushort4*)&lds[pos * cinP + c4 * 4];
            *(ushort4*)(drow + c4 * 4) = u;
        }
    }
    (void)wv;
}

// ---------------- MFMA conv body (verbatim R6 logic, smem carved) ----------------
// smem layout: wLds @0 (36,864B) | iLds @36,864 (43,008B) | dump @79,872 (1,024B)
template<int PR, int CO, int MODE>
__device__ void conv_body(char* smem,
                 const unsigned short* __restrict__ act,
                 const unsigned short* __restrict__ wt,
                 const unsigned short* __restrict__ guard,
                 void* __restrict__ outp,
                 int Cin, int Cout, int H, int W, int vx, int vy, int tid)
{
    constexpr int NT = (PR + 3) / 4;
    constexpr int MT = CO / 16;
    constexpr int ICELLS = (PR + 2) * 18;
    constexpr int ITASK = ICELLS * 4;
    constexpr int ITIN = (ITASK + 255) / 256;
    constexpr int IBYTES = ((ITASK + 63) & ~63) * 16;
    constexpr int WTASK = 9 * CO * 4;
    constexpr int WIT = (WTASK + 255) / 256;
    constexpr int WBYTES = 9 * CO * 64;
    constexpr int VL = WIT + ITIN;
    static_assert(VL == 7 || VL == 8 || VL == 11, "unexpected stage depth");
    static_assert(MODE == 0 || ((MODE == 3 || MODE == 4) && (NT % 2) == 0), "pool needs even NT");

    unsigned short* wLds = (unsigned short*)smem;
    unsigned short* iLds = (unsigned short*)(smem + 36864);
    unsigned short* dump = (unsigned short*)(smem + 79872);

    const int lane = tid & 63, wv = tid >> 6;
    const int half = lane >> 4, l15 = lane & 15;
    const int tilesX = W >> 4;
    const int pY = vx / tilesX, pX = vx - pY * tilesX;
    const int y0 = pY * PR, x0 = pX * 16;
    const int cob = vy;
    const int nCh = Cin >> 5;

    f32x4 acc[MT][NT];
#pragma unroll
    for (int mt = 0; mt < MT; ++mt)
#pragma unroll
        for (int nt = 0; nt < NT; ++nt) acc[mt][nt] = (f32x4){0.f, 0.f, 0.f, 0.f};

    auto STAGE = [&](int buf, int ci0) {
        const unsigned wB = (unsigned)(size_t)wLds + buf * WBYTES;
        const unsigned iB = (unsigned)(size_t)iLds + buf * IBYTES;
        const unsigned dB = (unsigned)(size_t)dump;
#pragma unroll
        for (int it = 0; it < WIT; ++it) {
            const int idx = it * 256 + tid;
            const int cell = idx >> 2, q = idx & 3;
            const int pos = cell / CO, co = cell % CO;
            const bool real = idx < WTASK;
            const unsigned short* src = real ?
                wt + (size_t)(pos * Cout + cob * CO + co) * Cin + ci0 + q * 8 : guard;
            const bool eng = (it * 256 + wv * 64) < WTASK;     // wave-uniform
            gl_lds16(src, __builtin_amdgcn_readfirstlane(
                eng ? wB + (unsigned)(it * 4096 + wv * 1024) : dB));
        }
#pragma unroll
        for (int it = 0; it < ITIN; ++it) {
            const int idx = it * 256 + tid;
            const int cell = idx >> 2, q = idx & 3;
            const int r = cell / 18, c = cell - r * 18;
            const int y = y0 - 1 + r, x = x0 - 1 + c;
            const bool ok = (idx < ITASK) & (y >= 0) & (y < H) & (x >= 0) & (x < W);
            const unsigned short* src = ok ?
                act + (size_t)(y * W + x) * Cin + ci0 + q * 8 : guard;
            const bool eng = (it * 256 + wv * 64) < ITASK;     // wave-uniform
            gl_lds16(src, __builtin_amdgcn_readfirstlane(
                eng ? iB + (unsigned)(it * 4096 + wv * 1024) : dB));
        }
    };

    STAGE(0, 0);
    for (int t = 0; t < nCh; ++t) {
        const int buf = t & 1;
        if (t + 1 < nCh) {
            STAGE(buf ^ 1, (t + 1) << 5);                // prefetch next chunk
            if constexpr (VL == 7)  asm volatile("s_waitcnt vmcnt(7)" ::: "memory");
            else if constexpr (VL == 8)  asm volatile("s_waitcnt vmcnt(8)" ::: "memory");
            else asm volatile("s_waitcnt vmcnt(11)" ::: "memory");
        } else {
            asm volatile("s_waitcnt vmcnt(0)" ::: "memory");
        }
        __builtin_amdgcn_s_barrier();
        asm volatile("" ::: "memory");

        const unsigned short* wP = wLds + buf * (WBYTES / 2);
        const unsigned short* iP = iLds + buf * (IBYTES / 2);
#pragma unroll
        for (int ky = 0; ky < 3; ++ky)
#pragma unroll
        for (int kx = 0; kx < 3; ++kx) {
            const int pos = ky * 3 + kx;
            short8 a[MT];
#pragma unroll
            for (int mt = 0; mt < MT; ++mt)
                a[mt] = *(const short8*)&wP[((pos * CO) + (mt << 4) + l15) * 32 + half * 8];
#pragma unroll
            for (int nt = 0; nt < NT; ++nt) {
                const short8 b = *(const short8*)
                    &iP[((wv * NT + nt + ky) * 18 + l15 + kx) * 32 + half * 8];
#pragma unroll
                for (int mt = 0; mt < MT; ++mt)
                    acc[mt][nt] = __builtin_amdgcn_mfma_f32_16x16x32_bf16(a[mt], b, acc[mt][nt], 0, 0, 0);
            }
        }
        asm volatile("" ::: "memory");
        __builtin_amdgcn_s_barrier();
    }

    // ---- epilogue ----
    const int xg = x0 + l15;
    if constexpr (MODE == 3 || MODE == 4) {
        const int Wo = W >> 1;
#pragma unroll
        for (int mt = 0; mt < MT; ++mt)
#pragma unroll
        for (int nt = 0; nt < NT; nt += 2) {
            f32x4 a;
#pragma unroll
            for (int j = 0; j < 4; ++j) a[j] = fmaxf(acc[mt][nt][j], acc[mt][nt + 1][j]);
            f32x4 m;
#pragma unroll
            for (int j = 0; j < 4; ++j) m[j] = fmaxf(a[j], __shfl_xor(a[j], 1, 64));
            if ((l15 & 1) == 0) {
                const int yo = (y0 + wv * NT + nt) >> 1;
                const int xo = xg >> 1;
                const int co = cob * CO + (mt << 4) + half * 4;
                if constexpr (MODE == 3) {
                    ushort4 u;
                    u.x = f2bf(fmaxf(m[0], 0.f));
                    u.y = f2bf(fmaxf(m[1], 0.f));
                    u.z = f2bf(fmaxf(m[2], 0.f));
                    u.w = f2bf(fmaxf(m[3], 0.f));
                    *(ushort4*)((unsigned short*)outp + ((size_t)(yo * Wo + xo) * Cout + co)) = u;
                } else {  // MODE 4: fp32 NCHW flatten [Cout][Ho][Wo]
                    float* op = (float*)outp;
                    const int hw = (W >> 1) * (W >> 1);
#pragma unroll
                    for (int j = 0; j < 4; ++j)
                        op[(size_t)(co + j) * hw + yo * Wo + xo] = fmaxf(m[j], 0.f);
                }
            }
        }
    } else {
#pragma unroll
        for (int mt = 0; mt < MT; ++mt)
#pragma unroll
        for (int nt = 0; nt < NT; ++nt) {
            const int yg = y0 + wv * NT + nt;
            const int co = cob * CO + (mt << 4) + half * 4;
            const size_t base = (size_t)(yg * W + xg) * Cout + co;
            ushort4 u;
            u.x = f2bf(fmaxf(acc[mt][nt][0], 0.f));
            u.y = f2bf(fmaxf(acc[mt][nt][1], 0.f));
            u.z = f2bf(fmaxf(acc[mt][nt][2], 0.f));
            u.w = f2bf(fmaxf(acc[mt][nt][3], 0.f));
            *(ushort4*)((unsigned short*)outp + base) = u;
        }
    }
}

// ---------------- L1 body: fp32 vector conv (Cin=3) -> NHWC bf16+relu ----
#define TILE 16
#define COB  32
__device__ void conv1_body(const float* __restrict__ in, const float* __restrict__ wt,
                           unsigned short* __restrict__ out, char* smem, int vb, int tid)
{
    const int Cin = 3, H = 256, W = 256, HW = H * W;
    float* sIn = (float*)smem;             // 2*648
    float* sWt = (float*)(smem + 5184);    // 2*768

    const int bx = vb & 15, by = (vb >> 4) & 15, co_blk = vb >> 8;
    const int co_grp = tid >> 6;
    const int lane = tid & 63;
    const int tx = lane & 7, ty = lane >> 3;
    const int x0 = bx * TILE, y0 = by * TILE;

    int iLdsI[3], iG[3], iSub[3]; bool iOk[3];
    int wLdsI[3], wG[3], wSub[3]; bool wOk[3];
#pragma unroll
    for (int j = 0; j < 3; ++j) {
        int i = tid + j * 256;
        iOk[j] = false; iLdsI[j] = 0; iG[j] = 0; iSub[j] = 0;
        if (i < 648) {
            int sub = i / 324; int r = i - sub * 324;
            int iy = r / 18;   int ix = r - iy * 18;
            iSub[j] = sub; iLdsI[j] = sub * 324 + r;
            int y = y0 - 1 + iy, x = x0 - 1 + ix;
            if (y >= 0 && y < H && x >= 0 && x < W) { iOk[j] = true; iG[j] = sub * HW + y * W + x; }
        }
        wOk[j] = false; wLdsI[j] = 0; wG[j] = 0; wSub[j] = 0;
        if (i < 576) {
            int sub = i / 288; int r = i - sub * 288;
            int col = r / 9;   int k = r - col * 9;
            wSub[j] = sub; wLdsI[j] = sub * 384 + col * 12 + k;
            wG[j] = ((co_blk * COB + col) * Cin + sub) * 9 + k;
            wOk[j] = true;
        }
    }

    float4 acc[8];
#pragma unroll
    for (int c = 0; c < 8; ++c) acc[c] = make_float4(0.f, 0.f, 0.f, 0.f);

    const int nSteps = 2;
    float rIn[3], rWt[3];
    {
#pragma unroll
        for (int j = 0; j < 3; ++j)
            rIn[j] = (iOk[j] && iSub[j] < 3) ? in[iG[j]] : 0.f;
#pragma unroll
        for (int j = 0; j < 3; ++j)
            rWt[j] = (wOk[j] && wSub[j] < 3) ? wt[wG[j]] : 0.f;
#pragma unroll
        for (int j = 0; j < 3; ++j) { if (tid + j * 256 < 648) sIn[iLdsI[j]] = rIn[j]; }
#pragma unroll
        for (int j = 0; j < 3; ++j) { if (tid + j * 256 < 576) sWt[wLdsI[j]] = rWt[j]; }
    }

    for (int t = 0; t < nSteps; ++t) {
        __syncthreads();
        const bool more = (t + 1) < nSteps;
        if (more) {
            const int ci0 = 2;
#pragma unroll
            for (int j = 0; j < 3; ++j)
                rIn[j] = (iOk[j] && (ci0 + iSub[j]) < 3) ? in[(size_t)ci0 * HW + iG[j]] : 0.f;
#pragma unroll
            for (int j = 0; j < 3; ++j)
                rWt[j] = (wOk[j] && (ci0 + wSub[j]) < 3) ? wt[(size_t)ci0 * 9 + wG[j]] : 0.f;
        }
        const int buf = t & 1;
        const float* sI = sIn + buf * 648;
        const float* sW = sWt + buf * 768;
#pragma unroll
        for (int sub = 0; sub < 2; ++sub) {
            float wv[4][4];
            const float* sp = sI + sub * 324 + (2 * ty) * 18 + 2 * tx;
#pragma unroll
            for (int r = 0; r < 4; ++r) {
                float2 a = *(const float2*)(sp + r * 18);
                float2 b = *(const float2*)(sp + r * 18 + 2);
                wv[r][0] = a.x; wv[r][1] = a.y; wv[r][2] = b.x; wv[r][3] = b.y;
            }
#pragma unroll
            for (int c = 0; c < 8; ++c) {
                const float* wp = sW + sub * 384 + (co_grp * 8 + c) * 12;
                float4 w0 = *(const float4*)wp;
                float4 w1 = *(const float4*)(wp + 4);
                float  w8 = wp[8];
                const float wk[9] = {w0.x, w0.y, w0.z, w0.w, w1.x, w1.y, w1.z, w1.w, w8};
                float* ac = (float*)&acc[c];
#pragma unroll
                for (int py = 0; py < 2; ++py)
#pragma unroll
                for (int px = 0; px < 2; ++px) {
                    float sacc = ac[py * 2 + px];
#pragma unroll
                    for (int kk = 0; kk < 9; ++kk)
                        sacc = fmaf(wv[py + kk / 3][px + kk % 3], wk[kk], sacc);
                    ac[py * 2 + px] = sacc;
                }
            }
        }
        if (more) {
            const int b2 = buf ^ 1;
#pragma unroll
            for (int j = 0; j < 3; ++j) { if (tid + j * 256 < 648) sIn[b2 * 648 + iLdsI[j]] = rIn[j]; }
#pragma unroll
            for (int j = 0; j < 3; ++j) { if (tid + j * 256 < 576) sWt[b2 * 768 + wLdsI[j]] = rWt[j]; }
        }
    }

    const int co0 = co_blk * COB + co_grp * 8;
#pragma unroll
    for (int py = 0; py < 2; ++py)
#pragma unroll
    for (int px = 0; px < 2; ++px) {
        const int y = y0 + 2 * ty + py, x = x0 + 2 * tx + px;
        unsigned short u8[8];
#pragma unroll
        for (int c = 0; c < 8; ++c)
            u8[c] = f2bf(fmaxf(((const float*)&acc[c])[py * 2 + px], 0.f));
        *(uint4*)(out + (size_t)(y * W + x) * 64 + co0) = *(uint4*)u8;
    }
}

// ---------------- uber kernel: wt + conv1 + L2..L13, 512 blocks ----------------
struct UberArgs {
    const float* x; const float* cw0;
    WtArgs wt;
    unsigned short* WT;
    unsigned short* guard;
    unsigned short* bA;
    unsigned short* bB;
    float* fcIn;
    unsigned* cnt;
    unsigned wOff[12];
};

__global__ __launch_bounds__(256, 2)
void uber_k(UberArgs A)
{
    __shared__ __align__(16) char smem[80896];
    const int bid = blockIdx.x, tid = threadIdx.x;
    unsigned gen = 0;

    // ---- stage 0: guard zero + conv1 + weight transform (grid-stride 1040 vb) ----
    if (bid == 0 && tid < 128) A.guard[tid] = 0;
    conv1_body(A.x, A.cw0, A.bA, smem, bid, tid);
    __syncthreads();
    for (int vb = bid; vb < 1040; vb += 512) {
        int l = 0;
#pragma unroll
        for (int i = 1; i < 12; ++i) l = (vb >= A.wt.d[i].blk0) ? i : l;
        wt_body(A.wt.d[l], vb - A.wt.d[l].blk0, A.WT, smem, tid);
        __syncthreads();
    }
    gridbar(A.cnt, gen, 512);
    // L2: 64->64 @256^2, pool -> bB @128^2          (256,2)=512
    conv_body<16, 32, 3>(smem, A.bA, A.WT + A.wOff[0], A.guard, A.bB, 64, 64, 256, 256, bid & 255, bid >> 8, tid);
    gridbar(A.cnt, gen, 512);
    // L3: 64->128 @128^2 -> bA                      (128,4)=512
    conv_body<8, 32, 0>(smem, A.bB, A.WT + A.wOff[1], A.guard, A.bA, 64, 128, 128, 128, bid & 127, bid >> 7, tid);
    gridbar(A.cnt, gen, 512);
    // L4: 128->128 @128^2, pool -> bB @64^2         (128,4)=512
    conv_body<8, 32, 3>(smem, A.bA, A.WT + A.wOff[2], A.guard, A.bB, 128, 128, 128, 128, bid & 127, bid >> 7, tid);
    gridbar(A.cnt, gen, 512);
    // L5: 128->256 @64^2 -> bA                      (32,8)=256
    if (bid < 256) conv_body<8, 32, 0>(smem, A.bB, A.WT + A.wOff[3], A.guard, A.bA, 128, 256, 64, 64, bid & 31, bid >> 5, tid);
    gridbar(A.cnt, gen, 512);
    // L6: 256->256 @64^2 -> bB                      (32,8)=256
    if (bid < 256) conv_body<8, 32, 0>(smem, A.bA, A.WT + A.wOff[4], A.guard, A.bB, 256, 256, 64, 64, bid & 31, bid >> 5, tid);
    gridbar(A.cnt, gen, 512);
    // L7: 256->256 @64^2, pool -> bA @32^2          (32,8)=256
    if (bid < 256) conv_body<8, 32, 3>(smem, A.bB, A.WT + A.wOff[5], A.guard, A.bA, 256, 256, 64, 64, bid & 31, bid >> 5, tid);
    gridbar(A.cnt, gen, 512);
    // L8: 256->512 @32^2 -> bB                      (16,16)=256
    if (bid < 256) conv_body<4, 32, 0>(smem, A.bA, A.WT + A.wOff[6], A.guard, A.bB, 256, 512, 32, 32, bid & 15, bid >> 4, tid);
    gridbar(A.cnt, gen, 512);
    // L9: 512->512 @32^2 -> bA                      (16,16)=256
    if (bid < 256) conv_body<4, 32, 0>(smem, A.bB, A.WT + A.wOff[7], A.guard, A.bA, 512, 512, 32, 32, bid & 15, bid >> 4, tid);
    gridbar(A.cnt, gen, 512);
    // L10: 512->512 @32^2, pool -> bB @16^2         (8,16)=128
    if (bid < 128) conv_body<8, 32, 3>(smem, A.bA, A.WT + A.wOff[8], A.guard, A.bB, 512, 512, 32, 32, bid & 7, bid >> 3, tid);
    gridbar(A.cnt, gen, 512);
    // L11: 512->512 @16^2 -> bA                     (4,16)=64
    if (bid < 64) conv_body<4, 32, 0>(smem, A.bB, A.WT + A.wOff[9], A.guard, A.bA, 512, 512, 16, 16, bid & 3, bid >> 2, tid);
    gridbar(A.cnt, gen, 512);
    // L12: 512->512 @16^2 -> bB                     (4,16)=64
    if (bid < 64) conv_body<4, 32, 0>(smem, A.bA, A.WT + A.wOff[10], A.guard, A.bB, 512, 512, 16, 16, bid & 3, bid >> 2, tid);
    gridbar(A.cnt, gen, 512);
    // L13: 512->512 @16^2, pool -> fp32 NCHW fcIn   (2,16)=32
    if (bid < 32) conv_body<8, 32, 4>(smem, A.bB, A.WT + A.wOff[11], A.guard, A.fcIn, 512, 512, 16, 16, bid & 1, bid >> 1, tid);
}

// ---------------- FC GEMV (fp32, weight-BW-bound) ----------------
__global__ __launch_bounds__(256)
void gemv_k(const float* __restrict__ Wm, const float* __restrict__ xv,
            float* __restrict__ y, int K)
{
    __shared__ float red[4];
    const int tid = threadIdx.x;
    const float4* row = (const float4*)(Wm + (size_t)blockIdx.x * K);
    const float4* x4  = (const float4*)xv;
    const int K4 = K >> 2;
    float sum = 0.f;
    for (int i = tid; i < K4; i += 256) {
        float4 a = row[i], b = x4[i];
        sum += a.x * b.x + a.y * b.y + a.z * b.z + a.w * b.w;
    }
#pragma unroll
    for (int off = 32; off > 0; off >>= 1) sum += __shfl_down(sum, off, 64);
    if ((tid & 63) == 0) red[tid >> 6] = sum;
    __syncthreads();
    if (tid == 0) y[blockIdx.x] = red[0] + red[1] + red[2] + red[3];
}

// ---------------- launcher ----------------
extern "C" void kernel_launch(void* const* d_in, const int* in_sizes, int n_in,
                              void* d_out, int out_size, void* d_ws, size_t ws_size,
                              hipStream_t stream)
{
    (void)in_sizes; (void)n_in; (void)out_size; (void)ws_size;
    const float* x = (const float*)d_in[0];
    const float* cw[13];
    for (int i = 0; i < 13; ++i) cw[i] = (const float*)d_in[5 + i];
    const float* fw1 = (const float*)d_in[18];
    const float* fw2 = (const float*)d_in[19];
    const float* fw3 = (const float*)d_in[20];
    float* outp = (float*)d_out;

    static const int CIN[12]  = {64, 64, 128, 128, 256, 256, 256, 512, 512, 512, 512, 512};
    static const int COUT[12] = {64, 128, 128, 256, 256, 256, 512, 512, 512, 512, 512, 512};

    char* ws = (char*)d_ws;
    size_t wOff[12]; size_t o = 0;
    for (int i = 0; i < 12; ++i) { wOff[i] = o; o += (size_t)9 * COUT[i] * CIN[i]; }
    unsigned short* WT = (unsigned short*)ws;               // 29.4 MB bf16
    unsigned short* guardp = WT + o;                        // 256 B zero guard
    size_t ao = ((o + 128) * 2 + 255) & ~(size_t)255;
    unsigned short* bA = (unsigned short*)(ws + ao);        // 8.39 MB
    unsigned short* bB = (unsigned short*)(ws + ao + 8388608);
    unsigned* cnt = (unsigned*)(ws + ao + 2 * 8388608);     // grid-barrier counter
    float* fcIn = (float*)bA;                               // L13 result (128 KB)
    float* F1 = (float*)bB;
    float* F2 = F1 + 4096;

    // zero the grid-barrier counter (workspace is poisoned between calls)
    hipMemsetAsync(cnt, 0, 256, stream);

    UberArgs ua;
    ua.x = x; ua.cw0 = cw[0];
    {
        int blk = 0; size_t oo = 0;
        for (int i = 0; i < 12; ++i) {
            ua.wt.d[i].src = cw[i + 1];
            ua.wt.d[i].dst = (unsigned)oo;
            ua.wt.d[i].cin = CIN[i];
            ua.wt.d[i].cout = COUT[i];
            ua.wt.d[i].blk0 = blk;
            oo += (size_t)9 * COUT[i] * CIN[i];
            blk += COUT[i] / 4;                             // total 1040
        }
    }
    ua.WT = WT; ua.guard = guardp; ua.bA = bA; ua.bB = bB;
    ua.fcIn = fcIn; ua.cnt = cnt;
    for (int i = 0; i < 12; ++i) ua.wOff[i] = (unsigned)wOff[i];

    uber_k<<<512, 256, 0, stream>>>(ua);

    // FC head (fp32, HBM-bound on weights)
    gemv_k<<<4096, 256, 0, stream>>>(fw1, fcIn, F1, 32768);
    gemv_k<<<4096, 256, 0, stream>>>(fw2, F1, F2, 4096);
    gemv_k<<<1000, 256, 0, stream>>>(fw3, F2, outp, 4096);
}

// Round 6
// 945.916 us; speedup vs baseline: 1.5376x; 1.5376x over previous
//
#include <hip/hip_runtime.h>
#include <cstddef>

// VGG-16 fwd, batch=1. R8: R6 structure (separate kernels; fusion refuted R4/R7) +
//  - init_k: weight transform + conv1 merged (independent, no barrier)
//  - DEPTH=3 triple-buffer, 2-deep prefetch (vmcnt(14)) on non-pool layers (PR=4)
//  - pooling layers keep proven DEPTH=2 (PR=8/16, LDS-bound)
//  - staging via global_load_lds_dwordx4, counted vmcnt, raw s_barrier
//  - dispatches: init, 12 convs, 3 gemv = 16
//  - FC: fp32 GEMV, weight-BW-bound (~100us floor)

typedef __attribute__((ext_vector_type(8))) short short8;
typedef __attribute__((ext_vector_type(4))) float f32x4;

__device__ inline unsigned short f2bf(float f) {
    unsigned int u = __builtin_bit_cast(unsigned int, f);
    u += 0x7FFF + ((u >> 16) & 1);          // RNE
    return (unsigned short)(u >> 16);
}

// direct global->LDS 16B: LDS dest = M0 + lane*16 (wave-uniform base in m0)
__device__ __forceinline__ void gl_lds16(const void* src, unsigned m0v) {
    asm volatile("s_mov_b32 m0, %1\n\t"
                 "global_load_lds_dwordx4 %0, off"
                 :: "v"(src), "s"(m0v) : "memory");
}

// ---------------- weight transform body: OIHW fp32 -> [pos][co][ci] bf16 ----
struct WtDesc { const float* src; unsigned dst; int cin; int cout; int blk0; };
struct WtArgs { WtDesc d[12]; };

__device__ void wt_body(const WtDesc& D, int relvb, unsigned short* __restrict__ wt,
                        char* smem, int tid)
{
    unsigned short* lds = (unsigned short*)smem + (tid >> 6) * 4680;  // 9*520 per wave
    const int lane = tid & 63;
    const int co = relvb * 4 + (tid >> 6);
    const int n = D.cin * 9;
    const int cinP = D.cin + 8;

    const float4* src = (const float4*)(D.src + (size_t)co * n);
    for (int i = lane; i < (n >> 2); i += 64) {
        float4 v = src[i];
        unsigned short b[4] = {f2bf(v.x), f2bf(v.y), f2bf(v.z), f2bf(v.w)};
        const int f0 = i * 4;
#pragma unroll
        for (int k = 0; k < 4; ++k) {
            const int f = f0 + k, ci = f / 9, pos = f - ci * 9;
            lds[pos * cinP + ci] = b[k];
        }
    }
    __syncthreads();
    unsigned short* dstb = wt + D.dst;
#pragma unroll 1
    for (int pos = 0; pos < 9; ++pos) {
        unsigned short* drow = dstb + ((size_t)pos * D.cout + co) * D.cin;
        for (int c4 = lane; c4 < (D.cin >> 2); c4 += 64) {
            ushort4 u = *(const ushort4*)&lds[pos * cinP + c4 * 4];
            *(ushort4*)(drow + c4 * 4) = u;
        }
    }
}

// ---------------- L1 body: fp32 vector conv (Cin=3) -> NHWC bf16+relu ----
#define TILE 16
#define COB  32
__device__ void conv1_body(const float* __restrict__ in, const float* __restrict__ wt,
                           unsigned short* __restrict__ out, char* smem, int vb, int tid)
{
    const int Cin = 3, H = 256, W = 256, HW = H * W;
    float* sIn = (float*)smem;             // 2*648
    float* sWt = (float*)(smem + 5184);    // 2*768

    const int bx = vb & 15, by = (vb >> 4) & 15, co_blk = vb >> 8;
    const int co_grp = tid >> 6;
    const int lane = tid & 63;
    const int tx = lane & 7, ty = lane >> 3;
    const int x0 = bx * TILE, y0 = by * TILE;

    int iLdsI[3], iG[3], iSub[3]; bool iOk[3];
    int wLdsI[3], wG[3], wSub[3]; bool wOk[3];
#pragma unroll
    for (int j = 0; j < 3; ++j) {
        int i = tid + j * 256;
        iOk[j] = false; iLdsI[j] = 0; iG[j] = 0; iSub[j] = 0;
        if (i < 648) {
            int sub = i / 324; int r = i - sub * 324;
            int iy = r / 18;   int ix = r - iy * 18;
            iSub[j] = sub; iLdsI[j] = sub * 324 + r;
            int y = y0 - 1 + iy, x = x0 - 1 + ix;
            if (y >= 0 && y < H && x >= 0 && x < W) { iOk[j] = true; iG[j] = sub * HW + y * W + x; }
        }
        wOk[j] = false; wLdsI[j] = 0; wG[j] = 0; wSub[j] = 0;
        if (i < 576) {
            int sub = i / 288; int r = i - sub * 288;
            int col = r / 9;   int k = r - col * 9;
            wSub[j] = sub; wLdsI[j] = sub * 384 + col * 12 + k;
            wG[j] = ((co_blk * COB + col) * Cin + sub) * 9 + k;
            wOk[j] = true;
        }
    }

    float4 acc[8];
#pragma unroll
    for (int c = 0; c < 8; ++c) acc[c] = make_float4(0.f, 0.f, 0.f, 0.f);

    const int nSteps = 2;
    float rIn[3], rWt[3];
    {
#pragma unroll
        for (int j = 0; j < 3; ++j)
            rIn[j] = (iOk[j] && iSub[j] < 3) ? in[iG[j]] : 0.f;
#pragma unroll
        for (int j = 0; j < 3; ++j)
            rWt[j] = (wOk[j] && wSub[j] < 3) ? wt[wG[j]] : 0.f;
#pragma unroll
        for (int j = 0; j < 3; ++j) { if (tid + j * 256 < 648) sIn[iLdsI[j]] = rIn[j]; }
#pragma unroll
        for (int j = 0; j < 3; ++j) { if (tid + j * 256 < 576) sWt[wLdsI[j]] = rWt[j]; }
    }

    for (int t = 0; t < nSteps; ++t) {
        __syncthreads();
        const bool more = (t + 1) < nSteps;
        if (more) {
            const int ci0 = 2;
#pragma unroll
            for (int j = 0; j < 3; ++j)
                rIn[j] = (iOk[j] && (ci0 + iSub[j]) < 3) ? in[(size_t)ci0 * HW + iG[j]] : 0.f;
#pragma unroll
            for (int j = 0; j < 3; ++j)
                rWt[j] = (wOk[j] && (ci0 + wSub[j]) < 3) ? wt[(size_t)ci0 * 9 + wG[j]] : 0.f;
        }
        const int buf = t & 1;
        const float* sI = sIn + buf * 648;
        const float* sW = sWt + buf * 768;
#pragma unroll
        for (int sub = 0; sub < 2; ++sub) {
            float wv[4][4];
            const float* sp = sI + sub * 324 + (2 * ty) * 18 + 2 * tx;
#pragma unroll
            for (int r = 0; r < 4; ++r) {
                float2 a = *(const float2*)(sp + r * 18);
                float2 b = *(const float2*)(sp + r * 18 + 2);
                wv[r][0] = a.x; wv[r][1] = a.y; wv[r][2] = b.x; wv[r][3] = b.y;
            }
#pragma unroll
            for (int c = 0; c < 8; ++c) {
                const float* wp = sW + sub * 384 + (co_grp * 8 + c) * 12;
                float4 w0 = *(const float4*)wp;
                float4 w1 = *(const float4*)(wp + 4);
                float  w8 = wp[8];
                const float wk[9] = {w0.x, w0.y, w0.z, w0.w, w1.x, w1.y, w1.z, w1.w, w8};
                float* ac = (float*)&acc[c];
#pragma unroll
                for (int py = 0; py < 2; ++py)
#pragma unroll
                for (int px = 0; px < 2; ++px) {
                    float sacc = ac[py * 2 + px];
#pragma unroll
                    for (int kk = 0; kk < 9; ++kk)
                        sacc = fmaf(wv[py + kk / 3][px + kk % 3], wk[kk], sacc);
                    ac[py * 2 + px] = sacc;
                }
            }
        }
        if (more) {
            const int b2 = buf ^ 1;
#pragma unroll
            for (int j = 0; j < 3; ++j) { if (tid + j * 256 < 648) sIn[b2 * 648 + iLdsI[j]] = rIn[j]; }
#pragma unroll
            for (int j = 0; j < 3; ++j) { if (tid + j * 256 < 576) sWt[b2 * 768 + wLdsI[j]] = rWt[j]; }
        }
    }

    const int co0 = co_blk * COB + co_grp * 8;
#pragma unroll
    for (int py = 0; py < 2; ++py)
#pragma unroll
    for (int px = 0; px < 2; ++px) {
        const int y = y0 + 2 * ty + py, x = x0 + 2 * tx + px;
        unsigned short u8[8];
#pragma unroll
        for (int c = 0; c < 8; ++c)
            u8[c] = f2bf(fmaxf(((const float*)&acc[c])[py * 2 + px], 0.f));
        *(uint4*)(out + (size_t)(y * W + x) * 64 + co0) = *(uint4*)u8;
    }
}

// ---------------- init kernel: conv1 + weight transform (independent work) ----
struct InitArgs {
    const float* x; const float* cw0;
    WtArgs wt;
    unsigned short* WT;
    unsigned short* guard;
    unsigned short* bA;
};

__global__ __launch_bounds__(256)
void init_k(InitArgs A)
{
    __shared__ __align__(16) char smem[40960];
    const int bid = blockIdx.x, tid = threadIdx.x;
    if (bid == 0 && tid < 128) A.guard[tid] = 0;
    conv1_body(A.x, A.cw0, A.bA, smem, bid, tid);
    __syncthreads();
    for (int vb = bid; vb < 1040; vb += 512) {
        int l = 0;
#pragma unroll
        for (int i = 1; i < 12; ++i) l = (vb >= A.wt.d[i].blk0) ? i : l;
        wt_body(A.wt.d[l], vb - A.wt.d[l].blk0, A.WT, smem, tid);
        __syncthreads();
    }
}

// ---------------- MFMA conv ----------------
// MODE: 0 relu+bf16 NHWC | 3 fused 2x2 maxpool+relu+bf16 NHWC | 4 pool+relu+fp32 NCHW
// DEPTH: 2 = double-buffer (1-deep prefetch), 3 = triple-buffer (2-deep prefetch)
template<int PR, int CO, int MODE, int DEPTH>
__global__ __launch_bounds__(256, 2)
void conv_mfma_k(const unsigned short* __restrict__ act,
                 const unsigned short* __restrict__ wt,
                 const unsigned short* __restrict__ guard,
                 void* __restrict__ outp,
                 int Cin, int Cout, int H, int W)
{
    constexpr int NT = (PR + 3) / 4;
    constexpr int MT = CO / 16;
    constexpr int ICELLS = (PR + 2) * 18;
    constexpr int ITASK = ICELLS * 4;
    constexpr int ITIN = (ITASK + 255) / 256;
    constexpr int IBYTES = ((ITASK + 63) & ~63) * 16;
    constexpr int WTASK = 9 * CO * 4;
    constexpr int WIT = (WTASK + 255) / 256;
    constexpr int WBYTES = 9 * CO * 64;
    constexpr int VL = WIT + ITIN;
    static_assert(VL == 7 || VL == 8 || VL == 11, "unexpected stage depth");
    static_assert(DEPTH == 2 || DEPTH == 3, "depth");
    static_assert(DEPTH == 2 || VL == 7, "triple-buffer only sized for PR=4");
    static_assert(DEPTH * (WBYTES + IBYTES) + 1024 <= 81920, "LDS over 2-block budget");
    static_assert(MODE == 0 || ((MODE == 3 || MODE == 4) && (NT % 2) == 0), "pool needs even NT");

    __shared__ __align__(16) unsigned short wLds[DEPTH * WBYTES / 2];
    __shared__ __align__(16) unsigned short iLds[DEPTH * IBYTES / 2];
    __shared__ __align__(16) unsigned short dump[512];

    const int tid = threadIdx.x;
    const int lane = tid & 63, wv = tid >> 6;
    const int half = lane >> 4, l15 = lane & 15;
    const int tilesX = W >> 4;
    const int pY = blockIdx.x / tilesX, pX = blockIdx.x - pY * tilesX;
    const int y0 = pY * PR, x0 = pX * 16;
    const int cob = blockIdx.y;
    const int nCh = Cin >> 5;

    f32x4 acc[MT][NT];
#pragma unroll
    for (int mt = 0; mt < MT; ++mt)
#pragma unroll
        for (int nt = 0; nt < NT; ++nt) acc[mt][nt] = (f32x4){0.f, 0.f, 0.f, 0.f};

    auto STAGE = [&](int buf, int ci0) {
        const unsigned wB = (unsigned)(size_t)wLds + buf * WBYTES;
        const unsigned iB = (unsigned)(size_t)iLds + buf * IBYTES;
        const unsigned dB = (unsigned)(size_t)dump;
#pragma unroll
        for (int it = 0; it < WIT; ++it) {
            const int idx = it * 256 + tid;
            const int cell = idx >> 2, q = idx & 3;
            const int pos = cell / CO, co = cell % CO;
            const bool real = idx < WTASK;
            const unsigned short* src = real ?
                wt + (size_t)(pos * Cout + cob * CO + co) * Cin + ci0 + q * 8 : guard;
            const bool eng = (it * 256 + wv * 64) < WTASK;     // wave-uniform
            gl_lds16(src, __builtin_amdgcn_readfirstlane(
                eng ? wB + (unsigned)(it * 4096 + wv * 1024) : dB));
        }
#pragma unroll
        for (int it = 0; it < ITIN; ++it) {
            const int idx = it * 256 + tid;
            const int cell = idx >> 2, q = idx & 3;
            const int r = cell / 18, c = cell - r * 18;
            const int y = y0 - 1 + r, x = x0 - 1 + c;
            const bool ok = (idx < ITASK) & (y >= 0) & (y < H) & (x >= 0) & (x < W);
            const unsigned short* src = ok ?
                act + (size_t)(y * W + x) * Cin + ci0 + q * 8 : guard;
            const bool eng = (it * 256 + wv * 64) < ITASK;     // wave-uniform
            gl_lds16(src, __builtin_amdgcn_readfirstlane(
                eng ? iB + (unsigned)(it * 4096 + wv * 1024) : dB));
        }
    };

    STAGE(0, 0);
    if constexpr (DEPTH == 3) STAGE(1, 32);    // all DEPTH=3 layers have nCh >= 2
    int bc = 0, bs = DEPTH - 1;
    for (int t = 0; t < nCh; ++t) {
        if (t + DEPTH - 1 < nCh) STAGE(bs, (t + DEPTH - 1) << 5);
        if constexpr (DEPTH == 2) {
            if (t + 1 < nCh) {
                if constexpr (VL == 8)  asm volatile("s_waitcnt vmcnt(8)" ::: "memory");
                else if constexpr (VL == 11) asm volatile("s_waitcnt vmcnt(11)" ::: "memory");
                else asm volatile("s_waitcnt vmcnt(7)" ::: "memory");
            } else {
                asm volatile("s_waitcnt vmcnt(0)" ::: "memory");
            }
        } else {
            if (t + 2 < nCh)      asm volatile("s_waitcnt vmcnt(14)" ::: "memory");
            else if (t + 1 < nCh) asm volatile("s_waitcnt vmcnt(7)" ::: "memory");
            else                  asm volatile("s_waitcnt vmcnt(0)" ::: "memory");
        }
        __builtin_amdgcn_s_barrier();
        asm volatile("" ::: "memory");

        const unsigned short* wP = wLds + bc * (WBYTES / 2);
        const unsigned short* iP = iLds + bc * (IBYTES / 2);
#pragma unroll
        for (int ky = 0; ky < 3; ++ky)
#pragma unroll
        for (int kx = 0; kx < 3; ++kx) {
            const int pos = ky * 3 + kx;
            short8 a[MT];
#pragma unroll
            for (int mt = 0; mt < MT; ++mt)
                a[mt] = *(const short8*)&wP[((pos * CO) + (mt << 4) + l15) * 32 + half * 8];
#pragma unroll
            for (int nt = 0; nt < NT; ++nt) {
                const short8 b = *(const short8*)
                    &iP[((wv * NT + nt + ky) * 18 + l15 + kx) * 32 + half * 8];
#pragma unroll
                for (int mt = 0; mt < MT; ++mt)
                    acc[mt][nt] = __builtin_amdgcn_mfma_f32_16x16x32_bf16(a[mt], b, acc[mt][nt], 0, 0, 0);
            }
        }
        asm volatile("" ::: "memory");
        __builtin_amdgcn_s_barrier();
        bc = (bc + 1 == DEPTH) ? 0 : bc + 1;
        bs = (bs + 1 == DEPTH) ? 0 : bs + 1;
    }

    // ---- epilogue: D layout col(lane&15)=pixel-x, row((lane>>4)*4+reg)=co ----
    const int xg = x0 + l15;
    if constexpr (MODE == 3 || MODE == 4) {
        const int Wo = W >> 1;
#pragma unroll
        for (int mt = 0; mt < MT; ++mt)
#pragma unroll
        for (int nt = 0; nt < NT; nt += 2) {
            f32x4 a;
#pragma unroll
            for (int j = 0; j < 4; ++j) a[j] = fmaxf(acc[mt][nt][j], acc[mt][nt + 1][j]);
            f32x4 m;
#pragma unroll
            for (int j = 0; j < 4; ++j) m[j] = fmaxf(a[j], __shfl_xor(a[j], 1, 64));
            if ((l15 & 1) == 0) {
                const int yo = (y0 + wv * NT + nt) >> 1;
                const int xo = xg >> 1;
                const int co = cob * CO + (mt << 4) + half * 4;
                if constexpr (MODE == 3) {
                    ushort4 u;
                    u.x = f2bf(fmaxf(m[0], 0.f));
                    u.y = f2bf(fmaxf(m[1], 0.f));
                    u.z = f2bf(fmaxf(m[2], 0.f));
                    u.w = f2bf(fmaxf(m[3], 0.f));
                    *(ushort4*)((unsigned short*)outp + ((size_t)(yo * Wo + xo) * Cout + co)) = u;
                } else {  // MODE 4: fp32 NCHW flatten [Cout][Ho][Wo]
                    float* op = (float*)outp;
                    const int hw = (W >> 1) * (W >> 1);
#pragma unroll
                    for (int j = 0; j < 4; ++j)
                        op[(size_t)(co + j) * hw + yo * Wo + xo] = fmaxf(m[j], 0.f);
                }
            }
        }
    } else {
#pragma unroll
        for (int mt = 0; mt < MT; ++mt)
#pragma unroll
        for (int nt = 0; nt < NT; ++nt) {
            const int yg = y0 + wv * NT + nt;
            const int co = cob * CO + (mt << 4) + half * 4;
            const size_t base = (size_t)(yg * W + xg) * Cout + co;
            ushort4 u;
            u.x = f2bf(fmaxf(acc[mt][nt][0], 0.f));
            u.y = f2bf(fmaxf(acc[mt][nt][1], 0.f));
            u.z = f2bf(fmaxf(acc[mt][nt][2], 0.f));
            u.w = f2bf(fmaxf(acc[mt][nt][3], 0.f));
            *(ushort4*)((unsigned short*)outp + base) = u;
        }
    }
}

// ---------------- FC GEMV (fp32, weight-BW-bound) ----------------
__global__ __launch_bounds__(256)
void gemv_k(const float* __restrict__ Wm, const float* __restrict__ xv,
            float* __restrict__ y, int K)
{
    __shared__ float red[4];
    const int tid = threadIdx.x;
    const float4* row = (const float4*)(Wm + (size_t)blockIdx.x * K);
    const float4* x4  = (const float4*)xv;
    const int K4 = K >> 2;
    float sum = 0.f;
    for (int i = tid; i < K4; i += 256) {
        float4 a = row[i], b = x4[i];
        sum += a.x * b.x + a.y * b.y + a.z * b.z + a.w * b.w;
    }
#pragma unroll
    for (int off = 32; off > 0; off >>= 1) sum += __shfl_down(sum, off, 64);
    if ((tid & 63) == 0) red[tid >> 6] = sum;
    __syncthreads();
    if (tid == 0) y[blockIdx.x] = red[0] + red[1] + red[2] + red[3];
}

// ---------------- launcher ----------------
extern "C" void kernel_launch(void* const* d_in, const int* in_sizes, int n_in,
                              void* d_out, int out_size, void* d_ws, size_t ws_size,
                              hipStream_t stream)
{
    (void)in_sizes; (void)n_in; (void)out_size; (void)ws_size;
    const float* x = (const float*)d_in[0];
    const float* cw[13];
    for (int i = 0; i < 13; ++i) cw[i] = (const float*)d_in[5 + i];
    const float* fw1 = (const float*)d_in[18];
    const float* fw2 = (const float*)d_in[19];
    const float* fw3 = (const float*)d_in[20];
    float* outp = (float*)d_out;

    static const int CIN[12]  = {64, 64, 128, 128, 256, 256, 256, 512, 512, 512, 512, 512};
    static const int COUT[12] = {64, 128, 128, 256, 256, 256, 512, 512, 512, 512, 512, 512};

    char* ws = (char*)d_ws;
    size_t wOff[12]; size_t o = 0;
    for (int i = 0; i < 12; ++i) { wOff[i] = o; o += (size_t)9 * COUT[i] * CIN[i]; }
    unsigned short* WT = (unsigned short*)ws;               // 29.4 MB bf16
    unsigned short* guardp = WT + o;                        // 256 B zero guard
    size_t ao = ((o + 128) * 2 + 255) & ~(size_t)255;
    unsigned short* bA = (unsigned short*)(ws + ao);        // 8.39 MB
    unsigned short* bB = (unsigned short*)(ws + ao + 8388608);
    float* fcIn = (float*)bA;                               // L13 result (128 KB)
    float* F1 = (float*)bB;
    float* F2 = F1 + 4096;

    // init: conv1 + fused weight transform (also zeroes halo guard)
    InitArgs ia;
    ia.x = x; ia.cw0 = cw[0]; ia.WT = WT; ia.guard = guardp; ia.bA = bA;
    {
        int blk = 0; size_t oo = 0;
        for (int i = 0; i < 12; ++i) {
            ia.wt.d[i].src = cw[i + 1];
            ia.wt.d[i].dst = (unsigned)oo;
            ia.wt.d[i].cin = CIN[i];
            ia.wt.d[i].cout = COUT[i];
            ia.wt.d[i].blk0 = blk;
            oo += (size_t)9 * COUT[i] * CIN[i];
            blk += COUT[i] / 4;                             // total 1040
        }
    }
    init_k<<<512, 256, 0, stream>>>(ia);

    // L2: 64->64 @256^2, pool -> bB @128^2            PR16 D2
    conv_mfma_k<16, 32, 3, 2><<<dim3(256, 2), 256, 0, stream>>>(bA, WT + wOff[0], guardp, bB, 64, 64, 256, 256);
    // L3: 64->128 @128^2 -> bA                        PR4 D3
    conv_mfma_k<4, 32, 0, 3><<<dim3(256, 4), 256, 0, stream>>>(bB, WT + wOff[1], guardp, bA, 64, 128, 128, 128);
    // L4: 128->128 @128^2, pool -> bB @64^2           PR8 D2
    conv_mfma_k<8, 32, 3, 2><<<dim3(128, 4), 256, 0, stream>>>(bA, WT + wOff[2], guardp, bB, 128, 128, 128, 128);
    // L5: 128->256 @64^2 -> bA                        PR4 D3
    conv_mfma_k<4, 32, 0, 3><<<dim3(64, 8), 256, 0, stream>>>(bB, WT + wOff[3], guardp, bA, 128, 256, 64, 64);
    // L6: 256->256 @64^2 -> bB                        PR4 D3
    conv_mfma_k<4, 32, 0, 3><<<dim3(64, 8), 256, 0, stream>>>(bA, WT + wOff[4], guardp, bB, 256, 256, 64, 64);
    // L7: 256->256 @64^2, pool -> bA @32^2            PR8 D2
    conv_mfma_k<8, 32, 3, 2><<<dim3(32, 8), 256, 0, stream>>>(bB, WT + wOff[5], guardp, bA, 256, 256, 64, 64);
    // L8: 256->512 @32^2 -> bB                        PR4 D3
    conv_mfma_k<4, 32, 0, 3><<<dim3(16, 16), 256, 0, stream>>>(bA, WT + wOff[6], guardp, bB, 256, 512, 32, 32);
    // L9: 512->512 @32^2 -> bA                        PR4 D3
    conv_mfma_k<4, 32, 0, 3><<<dim3(16, 16), 256, 0, stream>>>(bB, WT + wOff[7], guardp, bA, 512, 512, 32, 32);
    // L10: 512->512 @32^2, pool -> bB @16^2           PR8 D2
    conv_mfma_k<8, 32, 3, 2><<<dim3(8, 16), 256, 0, stream>>>(bA, WT + wOff[8], guardp, bB, 512, 512, 32, 32);
    // L11: 512->512 @16^2 -> bA                       PR4 D3
    conv_mfma_k<4, 32, 0, 3><<<dim3(4, 16), 256, 0, stream>>>(bB, WT + wOff[9], guardp, bA, 512, 512, 16, 16);
    // L12: 512->512 @16^2 -> bB                       PR4 D3
    conv_mfma_k<4, 32, 0, 3><<<dim3(4, 16), 256, 0, stream>>>(bA, WT + wOff[10], guardp, bB, 512, 512, 16, 16);
    // L13: 512->512 @16^2, pool -> fp32 NCHW fcIn     PR8 D2 MODE4
    conv_mfma_k<8, 32, 4, 2><<<dim3(2, 16), 256, 0, stream>>>(bB, WT + wOff[11], guardp, fcIn, 512, 512, 16, 16);

    // FC head (fp32, HBM-bound on weights)
    gemv_k<<<4096, 256, 0, stream>>>(fw1, fcIn, F1, 32768);
    gemv_k<<<4096, 256, 0, stream>>>(fw2, F1, F2, 4096);
    gemv_k<<<1000, 256, 0, stream>>>(fw3, F2, outp, 4096);
}

// Round 7
// 941.856 us; speedup vs baseline: 1.5442x; 1.0043x over previous
//
#include <hip/hip_runtime.h>
#include <cstddef>

// VGG-16 fwd, batch=1. R9: consolidation = R6 conv configs (best, 940us) + init_k merge.
//  - all convs DEPTH=2 double-buffer (D3/PR4-everywhere regression reverted)
//  - init_k: conv1 + fused weight transform in one launch (independent work)
//  - staging via global_load_lds_dwordx4, counted vmcnt, raw s_barrier
//  - dispatches: init, 12 convs, 3 gemv = 16
//  - FC: fp32 GEMV, weight-BW-bound (~100us floor)
//  - fusion via grid barriers refuted twice (R4, R7): per-layer dispatch is cheaper

typedef __attribute__((ext_vector_type(8))) short short8;
typedef __attribute__((ext_vector_type(4))) float f32x4;

__device__ inline unsigned short f2bf(float f) {
    unsigned int u = __builtin_bit_cast(unsigned int, f);
    u += 0x7FFF + ((u >> 16) & 1);          // RNE
    return (unsigned short)(u >> 16);
}

// direct global->LDS 16B: LDS dest = M0 + lane*16 (wave-uniform base in m0)
__device__ __forceinline__ void gl_lds16(const void* src, unsigned m0v) {
    asm volatile("s_mov_b32 m0, %1\n\t"
                 "global_load_lds_dwordx4 %0, off"
                 :: "v"(src), "s"(m0v) : "memory");
}

// ---------------- weight transform body: OIHW fp32 -> [pos][co][ci] bf16 ----
struct WtDesc { const float* src; unsigned dst; int cin; int cout; int blk0; };
struct WtArgs { WtDesc d[12]; };

__device__ void wt_body(const WtDesc& D, int relvb, unsigned short* __restrict__ wt,
                        char* smem, int tid)
{
    unsigned short* lds = (unsigned short*)smem + (tid >> 6) * 4680;  // 9*520 per wave
    const int lane = tid & 63;
    const int co = relvb * 4 + (tid >> 6);
    const int n = D.cin * 9;
    const int cinP = D.cin + 8;

    const float4* src = (const float4*)(D.src + (size_t)co * n);
    for (int i = lane; i < (n >> 2); i += 64) {
        float4 v = src[i];
        unsigned short b[4] = {f2bf(v.x), f2bf(v.y), f2bf(v.z), f2bf(v.w)};
        const int f0 = i * 4;
#pragma unroll
        for (int k = 0; k < 4; ++k) {
            const int f = f0 + k, ci = f / 9, pos = f - ci * 9;
            lds[pos * cinP + ci] = b[k];
        }
    }
    __syncthreads();
    unsigned short* dstb = wt + D.dst;
#pragma unroll 1
    for (int pos = 0; pos < 9; ++pos) {
        unsigned short* drow = dstb + ((size_t)pos * D.cout + co) * D.cin;
        for (int c4 = lane; c4 < (D.cin >> 2); c4 += 64) {
            ushort4 u = *(const ushort4*)&lds[pos * cinP + c4 * 4];
            *(ushort4*)(drow + c4 * 4) = u;
        }
    }
}

// ---------------- L1 body: fp32 vector conv (Cin=3) -> NHWC bf16+relu ----
#define TILE 16
#define COB  32
__device__ void conv1_body(const float* __restrict__ in, const float* __restrict__ wt,
                           unsigned short* __restrict__ out, char* smem, int vb, int tid)
{
    const int Cin = 3, H = 256, W = 256, HW = H * W;
    float* sIn = (float*)smem;             // 2*648
    float* sWt = (float*)(smem + 5184);    // 2*768

    const int bx = vb & 15, by = (vb >> 4) & 15, co_blk = vb >> 8;
    const int co_grp = tid >> 6;
    const int lane = tid & 63;
    const int tx = lane & 7, ty = lane >> 3;
    const int x0 = bx * TILE, y0 = by * TILE;

    int iLdsI[3], iG[3], iSub[3]; bool iOk[3];
    int wLdsI[3], wG[3], wSub[3]; bool wOk[3];
#pragma unroll
    for (int j = 0; j < 3; ++j) {
        int i = tid + j * 256;
        iOk[j] = false; iLdsI[j] = 0; iG[j] = 0; iSub[j] = 0;
        if (i < 648) {
            int sub = i / 324; int r = i - sub * 324;
            int iy = r / 18;   int ix = r - iy * 18;
            iSub[j] = sub; iLdsI[j] = sub * 324 + r;
            int y = y0 - 1 + iy, x = x0 - 1 + ix;
            if (y >= 0 && y < H && x >= 0 && x < W) { iOk[j] = true; iG[j] = sub * HW + y * W + x; }
        }
        wOk[j] = false; wLdsI[j] = 0; wG[j] = 0; wSub[j] = 0;
        if (i < 576) {
            int sub = i / 288; int r = i - sub * 288;
            int col = r / 9;   int k = r - col * 9;
            wSub[j] = sub; wLdsI[j] = sub * 384 + col * 12 + k;
            wG[j] = ((co_blk * COB + col) * Cin + sub) * 9 + k;
            wOk[j] = true;
        }
    }

    float4 acc[8];
#pragma unroll
    for (int c = 0; c < 8; ++c) acc[c] = make_float4(0.f, 0.f, 0.f, 0.f);

    const int nSteps = 2;
    float rIn[3], rWt[3];
    {
#pragma unroll
        for (int j = 0; j < 3; ++j)
            rIn[j] = (iOk[j] && iSub[j] < 3) ? in[iG[j]] : 0.f;
#pragma unroll
        for (int j = 0; j < 3; ++j)
            rWt[j] = (wOk[j] && wSub[j] < 3) ? wt[wG[j]] : 0.f;
#pragma unroll
        for (int j = 0; j < 3; ++j) { if (tid + j * 256 < 648) sIn[iLdsI[j]] = rIn[j]; }
#pragma unroll
        for (int j = 0; j < 3; ++j) { if (tid + j * 256 < 576) sWt[wLdsI[j]] = rWt[j]; }
    }

    for (int t = 0; t < nSteps; ++t) {
        __syncthreads();
        const bool more = (t + 1) < nSteps;
        if (more) {
            const int ci0 = 2;
#pragma unroll
            for (int j = 0; j < 3; ++j)
                rIn[j] = (iOk[j] && (ci0 + iSub[j]) < 3) ? in[(size_t)ci0 * HW + iG[j]] : 0.f;
#pragma unroll
            for (int j = 0; j < 3; ++j)
                rWt[j] = (wOk[j] && (ci0 + wSub[j]) < 3) ? wt[(size_t)ci0 * 9 + wG[j]] : 0.f;
        }
        const int buf = t & 1;
        const float* sI = sIn + buf * 648;
        const float* sW = sWt + buf * 768;
#pragma unroll
        for (int sub = 0; sub < 2; ++sub) {
            float wv[4][4];
            const float* sp = sI + sub * 324 + (2 * ty) * 18 + 2 * tx;
#pragma unroll
            for (int r = 0; r < 4; ++r) {
                float2 a = *(const float2*)(sp + r * 18);
                float2 b = *(const float2*)(sp + r * 18 + 2);
                wv[r][0] = a.x; wv[r][1] = a.y; wv[r][2] = b.x; wv[r][3] = b.y;
            }
#pragma unroll
            for (int c = 0; c < 8; ++c) {
                const float* wp = sW + sub * 384 + (co_grp * 8 + c) * 12;
                float4 w0 = *(const float4*)wp;
                float4 w1 = *(const float4*)(wp + 4);
                float  w8 = wp[8];
                const float wk[9] = {w0.x, w0.y, w0.z, w0.w, w1.x, w1.y, w1.z, w1.w, w8};
                float* ac = (float*)&acc[c];
#pragma unroll
                for (int py = 0; py < 2; ++py)
#pragma unroll
                for (int px = 0; px < 2; ++px) {
                    float sacc = ac[py * 2 + px];
#pragma unroll
                    for (int kk = 0; kk < 9; ++kk)
                        sacc = fmaf(wv[py + kk / 3][px + kk % 3], wk[kk], sacc);
                    ac[py * 2 + px] = sacc;
                }
            }
        }
        if (more) {
            const int b2 = buf ^ 1;
#pragma unroll
            for (int j = 0; j < 3; ++j) { if (tid + j * 256 < 648) sIn[b2 * 648 + iLdsI[j]] = rIn[j]; }
#pragma unroll
            for (int j = 0; j < 3; ++j) { if (tid + j * 256 < 576) sWt[b2 * 768 + wLdsI[j]] = rWt[j]; }
        }
    }

    const int co0 = co_blk * COB + co_grp * 8;
#pragma unroll
    for (int py = 0; py < 2; ++py)
#pragma unroll
    for (int px = 0; px < 2; ++px) {
        const int y = y0 + 2 * ty + py, x = x0 + 2 * tx + px;
        unsigned short u8[8];
#pragma unroll
        for (int c = 0; c < 8; ++c)
            u8[c] = f2bf(fmaxf(((const float*)&acc[c])[py * 2 + px], 0.f));
        *(uint4*)(out + (size_t)(y * W + x) * 64 + co0) = *(uint4*)u8;
    }
}

// ---------------- init kernel: conv1 + weight transform (independent work) ----
struct InitArgs {
    const float* x; const float* cw0;
    WtArgs wt;
    unsigned short* WT;
    unsigned short* guard;
    unsigned short* bA;
};

__global__ __launch_bounds__(256)
void init_k(InitArgs A)
{
    __shared__ __align__(16) char smem[40960];
    const int bid = blockIdx.x, tid = threadIdx.x;
    if (bid == 0 && tid < 128) A.guard[tid] = 0;
    conv1_body(A.x, A.cw0, A.bA, smem, bid, tid);
    __syncthreads();
    for (int vb = bid; vb < 1040; vb += 512) {
        int l = 0;
#pragma unroll
        for (int i = 1; i < 12; ++i) l = (vb >= A.wt.d[i].blk0) ? i : l;
        wt_body(A.wt.d[l], vb - A.wt.d[l].blk0, A.WT, smem, tid);
        __syncthreads();
    }
}

// ---------------- MFMA conv ----------------
// MODE: 0 relu+bf16 NHWC | 3 fused 2x2 maxpool+relu+bf16 NHWC | 4 pool+relu+fp32 NCHW
template<int PR, int CO, int MODE>
__global__ __launch_bounds__(256, 2)
void conv_mfma_k(const unsigned short* __restrict__ act,
                 const unsigned short* __restrict__ wt,
                 const unsigned short* __restrict__ guard,
                 void* __restrict__ outp,
                 int Cin, int Cout, int H, int W)
{
    constexpr int NT = (PR + 3) / 4;
    constexpr int MT = CO / 16;
    constexpr int ICELLS = (PR + 2) * 18;
    constexpr int ITASK = ICELLS * 4;
    constexpr int ITIN = (ITASK + 255) / 256;
    constexpr int IBYTES = ((ITASK + 63) & ~63) * 16;
    constexpr int WTASK = 9 * CO * 4;
    constexpr int WIT = (WTASK + 255) / 256;
    constexpr int WBYTES = 9 * CO * 64;
    constexpr int VL = WIT + ITIN;
    static_assert(VL == 7 || VL == 8 || VL == 11, "unexpected stage depth");
    static_assert(2 * (WBYTES + IBYTES) + 1024 <= 81920, "LDS over 2-block budget");
    static_assert(MODE == 0 || ((MODE == 3 || MODE == 4) && (NT % 2) == 0), "pool needs even NT");

    __shared__ __align__(16) unsigned short wLds[WBYTES];           // 2 bufs
    __shared__ __align__(16) unsigned short iLds[IBYTES];           // 2 bufs
    __shared__ __align__(16) unsigned short dump[512];

    const int tid = threadIdx.x;
    const int lane = tid & 63, wv = tid >> 6;
    const int half = lane >> 4, l15 = lane & 15;
    const int tilesX = W >> 4;
    const int pY = blockIdx.x / tilesX, pX = blockIdx.x - pY * tilesX;
    const int y0 = pY * PR, x0 = pX * 16;
    const int cob = blockIdx.y;
    const int nCh = Cin >> 5;

    f32x4 acc[MT][NT];
#pragma unroll
    for (int mt = 0; mt < MT; ++mt)
#pragma unroll
        for (int nt = 0; nt < NT; ++nt) acc[mt][nt] = (f32x4){0.f, 0.f, 0.f, 0.f};

    auto STAGE = [&](int buf, int ci0) {
        const unsigned wB = (unsigned)(size_t)wLds + buf * WBYTES;
        const unsigned iB = (unsigned)(size_t)iLds + buf * IBYTES;
        const unsigned dB = (unsigned)(size_t)dump;
#pragma unroll
        for (int it = 0; it < WIT; ++it) {
            const int idx = it * 256 + tid;
            const int cell = idx >> 2, q = idx & 3;
            const int pos = cell / CO, co = cell % CO;
            const bool real = idx < WTASK;
            const unsigned short* src = real ?
                wt + (size_t)(pos * Cout + cob * CO + co) * Cin + ci0 + q * 8 : guard;
            const bool eng = (it * 256 + wv * 64) < WTASK;     // wave-uniform
            gl_lds16(src, __builtin_amdgcn_readfirstlane(
                eng ? wB + (unsigned)(it * 4096 + wv * 1024) : dB));
        }
#pragma unroll
        for (int it = 0; it < ITIN; ++it) {
            const int idx = it * 256 + tid;
            const int cell = idx >> 2, q = idx & 3;
            const int r = cell / 18, c = cell - r * 18;
            const int y = y0 - 1 + r, x = x0 - 1 + c;
            const bool ok = (idx < ITASK) & (y >= 0) & (y < H) & (x >= 0) & (x < W);
            const unsigned short* src = ok ?
                act + (size_t)(y * W + x) * Cin + ci0 + q * 8 : guard;
            const bool eng = (it * 256 + wv * 64) < ITASK;     // wave-uniform
            gl_lds16(src, __builtin_amdgcn_readfirstlane(
                eng ? iB + (unsigned)(it * 4096 + wv * 1024) : dB));
        }
    };

    STAGE(0, 0);
    for (int t = 0; t < nCh; ++t) {
        const int buf = t & 1;
        if (t + 1 < nCh) {
            STAGE(buf ^ 1, (t + 1) << 5);                // prefetch next chunk
            if constexpr (VL == 7)  asm volatile("s_waitcnt vmcnt(7)" ::: "memory");
            else if constexpr (VL == 8)  asm volatile("s_waitcnt vmcnt(8)" ::: "memory");
            else asm volatile("s_waitcnt vmcnt(11)" ::: "memory");
        } else {
            asm volatile("s_waitcnt vmcnt(0)" ::: "memory");
        }
        __builtin_amdgcn_s_barrier();
        asm volatile("" ::: "memory");

        const unsigned short* wP = wLds + buf * (WBYTES / 2);
        const unsigned short* iP = iLds + buf * (IBYTES / 2);
#pragma unroll
        for (int ky = 0; ky < 3; ++ky)
#pragma unroll
        for (int kx = 0; kx < 3; ++kx) {
            const int pos = ky * 3 + kx;
            short8 a[MT];
#pragma unroll
            for (int mt = 0; mt < MT; ++mt)
                a[mt] = *(const short8*)&wP[((pos * CO) + (mt << 4) + l15) * 32 + half * 8];
#pragma unroll
            for (int nt = 0; nt < NT; ++nt) {
                const short8 b = *(const short8*)
                    &iP[((wv * NT + nt + ky) * 18 + l15 + kx) * 32 + half * 8];
#pragma unroll
                for (int mt = 0; mt < MT; ++mt)
                    acc[mt][nt] = __builtin_amdgcn_mfma_f32_16x16x32_bf16(a[mt], b, acc[mt][nt], 0, 0, 0);
            }
        }
        asm volatile("" ::: "memory");
        __builtin_amdgcn_s_barrier();
    }

    // ---- epilogue: D layout col(lane&15)=pixel-x, row((lane>>4)*4+reg)=co ----
    const int xg = x0 + l15;
    if constexpr (MODE == 3 || MODE == 4) {
        const int Wo = W >> 1;
#pragma unroll
        for (int mt = 0; mt < MT; ++mt)
#pragma unroll
        for (int nt = 0; nt < NT; nt += 2) {
            f32x4 a;
#pragma unroll
            for (int j = 0; j < 4; ++j) a[j] = fmaxf(acc[mt][nt][j], acc[mt][nt + 1][j]);
            f32x4 m;
#pragma unroll
            for (int j = 0; j < 4; ++j) m[j] = fmaxf(a[j], __shfl_xor(a[j], 1, 64));
            if ((l15 & 1) == 0) {
                const int yo = (y0 + wv * NT + nt) >> 1;
                const int xo = xg >> 1;
                const int co = cob * CO + (mt << 4) + half * 4;
                if constexpr (MODE == 3) {
                    ushort4 u;
                    u.x = f2bf(fmaxf(m[0], 0.f));
                    u.y = f2bf(fmaxf(m[1], 0.f));
                    u.z = f2bf(fmaxf(m[2], 0.f));
                    u.w = f2bf(fmaxf(m[3], 0.f));
                    *(ushort4*)((unsigned short*)outp + ((size_t)(yo * Wo + xo) * Cout + co)) = u;
                } else {  // MODE 4: fp32 NCHW flatten [Cout][Ho][Wo]
                    float* op = (float*)outp;
                    const int hw = (W >> 1) * (W >> 1);
#pragma unroll
                    for (int j = 0; j < 4; ++j)
                        op[(size_t)(co + j) * hw + yo * Wo + xo] = fmaxf(m[j], 0.f);
                }
            }
        }
    } else {
#pragma unroll
        for (int mt = 0; mt < MT; ++mt)
#pragma unroll
        for (int nt = 0; nt < NT; ++nt) {
            const int yg = y0 + wv * NT + nt;
            const int co = cob * CO + (mt << 4) + half * 4;
            const size_t base = (size_t)(yg * W + xg) * Cout + co;
            ushort4 u;
            u.x = f2bf(fmaxf(acc[mt][nt][0], 0.f));
            u.y = f2bf(fmaxf(acc[mt][nt][1], 0.f));
            u.z = f2bf(fmaxf(acc[mt][nt][2], 0.f));
            u.w = f2bf(fmaxf(acc[mt][nt][3], 0.f));
            *(ushort4*)((unsigned short*)outp + base) = u;
        }
    }
}

// ---------------- FC GEMV (fp32, weight-BW-bound) ----------------
__global__ __launch_bounds__(256)
void gemv_k(const float* __restrict__ Wm, const float* __restrict__ xv,
            float* __restrict__ y, int K)
{
    __shared__ float red[4];
    const int tid = threadIdx.x;
    const float4* row = (const float4*)(Wm + (size_t)blockIdx.x * K);
    const float4* x4  = (const float4*)xv;
    const int K4 = K >> 2;
    float sum = 0.f;
    for (int i = tid; i < K4; i += 256) {
        float4 a = row[i], b = x4[i];
        sum += a.x * b.x + a.y * b.y + a.z * b.z + a.w * b.w;
    }
#pragma unroll
    for (int off = 32; off > 0; off >>= 1) sum += __shfl_down(sum, off, 64);
    if ((tid & 63) == 0) red[tid >> 6] = sum;
    __syncthreads();
    if (tid == 0) y[blockIdx.x] = red[0] + red[1] + red[2] + red[3];
}

// ---------------- launcher ----------------
extern "C" void kernel_launch(void* const* d_in, const int* in_sizes, int n_in,
                              void* d_out, int out_size, void* d_ws, size_t ws_size,
                              hipStream_t stream)
{
    (void)in_sizes; (void)n_in; (void)out_size; (void)ws_size;
    const float* x = (const float*)d_in[0];
    const float* cw[13];
    for (int i = 0; i < 13; ++i) cw[i] = (const float*)d_in[5 + i];
    const float* fw1 = (const float*)d_in[18];
    const float* fw2 = (const float*)d_in[19];
    const float* fw3 = (const float*)d_in[20];
    float* outp = (float*)d_out;

    static const int CIN[12]  = {64, 64, 128, 128, 256, 256, 256, 512, 512, 512, 512, 512};
    static const int COUT[12] = {64, 128, 128, 256, 256, 256, 512, 512, 512, 512, 512, 512};

    char* ws = (char*)d_ws;
    size_t wOff[12]; size_t o = 0;
    for (int i = 0; i < 12; ++i) { wOff[i] = o; o += (size_t)9 * COUT[i] * CIN[i]; }
    unsigned short* WT = (unsigned short*)ws;               // 29.4 MB bf16
    unsigned short* guardp = WT + o;                        // 256 B zero guard
    size_t ao = ((o + 128) * 2 + 255) & ~(size_t)255;
    unsigned short* bA = (unsigned short*)(ws + ao);        // 8.39 MB
    unsigned short* bB = (unsigned short*)(ws + ao + 8388608);
    float* fcIn = (float*)bA;                               // L13 result (128 KB)
    float* F1 = (float*)bB;
    float* F2 = F1 + 4096;

    // init: conv1 + fused weight transform (also zeroes halo guard)
    InitArgs ia;
    ia.x = x; ia.cw0 = cw[0]; ia.WT = WT; ia.guard = guardp; ia.bA = bA;
    {
        int blk = 0; size_t oo = 0;
        for (int i = 0; i < 12; ++i) {
            ia.wt.d[i].src = cw[i + 1];
            ia.wt.d[i].dst = (unsigned)oo;
            ia.wt.d[i].cin = CIN[i];
            ia.wt.d[i].cout = COUT[i];
            ia.wt.d[i].blk0 = blk;
            oo += (size_t)9 * COUT[i] * CIN[i];
            blk += COUT[i] / 4;                             // total 1040
        }
    }
    init_k<<<512, 256, 0, stream>>>(ia);

    // L2: 64->64 @256^2, pool -> bB @128^2            PR16
    conv_mfma_k<16, 32, 3><<<dim3(256, 2), 256, 0, stream>>>(bA, WT + wOff[0], guardp, bB, 64, 64, 256, 256);
    // L3: 64->128 @128^2 -> bA                        PR8
    conv_mfma_k<8, 32, 0><<<dim3(128, 4), 256, 0, stream>>>(bB, WT + wOff[1], guardp, bA, 64, 128, 128, 128);
    // L4: 128->128 @128^2, pool -> bB @64^2           PR8
    conv_mfma_k<8, 32, 3><<<dim3(128, 4), 256, 0, stream>>>(bA, WT + wOff[2], guardp, bB, 128, 128, 128, 128);
    // L5: 128->256 @64^2 -> bA                        PR8
    conv_mfma_k<8, 32, 0><<<dim3(32, 8), 256, 0, stream>>>(bB, WT + wOff[3], guardp, bA, 128, 256, 64, 64);
    // L6: 256->256 @64^2 -> bB                        PR8
    conv_mfma_k<8, 32, 0><<<dim3(32, 8), 256, 0, stream>>>(bA, WT + wOff[4], guardp, bB, 256, 256, 64, 64);
    // L7: 256->256 @64^2, pool -> bA @32^2            PR8
    conv_mfma_k<8, 32, 3><<<dim3(32, 8), 256, 0, stream>>>(bB, WT + wOff[5], guardp, bA, 256, 256, 64, 64);
    // L8: 256->512 @32^2 -> bB                        PR4
    conv_mfma_k<4, 32, 0><<<dim3(16, 16), 256, 0, stream>>>(bA, WT + wOff[6], guardp, bB, 256, 512, 32, 32);
    // L9: 512->512 @32^2 -> bA                        PR4
    conv_mfma_k<4, 32, 0><<<dim3(16, 16), 256, 0, stream>>>(bB, WT + wOff[7], guardp, bA, 512, 512, 32, 32);
    // L10: 512->512 @32^2, pool -> bB @16^2           PR8
    conv_mfma_k<8, 32, 3><<<dim3(8, 16), 256, 0, stream>>>(bA, WT + wOff[8], guardp, bB, 512, 512, 32, 32);
    // L11: 512->512 @16^2 -> bA                       PR4
    conv_mfma_k<4, 32, 0><<<dim3(4, 16), 256, 0, stream>>>(bB, WT + wOff[9], guardp, bA, 512, 512, 16, 16);
    // L12: 512->512 @16^2 -> bB                       PR4
    conv_mfma_k<4, 32, 0><<<dim3(4, 16), 256, 0, stream>>>(bA, WT + wOff[10], guardp, bB, 512, 512, 16, 16);
    // L13: 512->512 @16^2, pool -> fp32 NCHW fcIn     PR8 MODE4
    conv_mfma_k<8, 32, 4><<<dim3(2, 16), 256, 0, stream>>>(bB, WT + wOff[11], guardp, fcIn, 512, 512, 16, 16);

    // FC head (fp32, HBM-bound on weights)
    gemv_k<<<4096, 256, 0, stream>>>(fw1, fcIn, F1, 32768);
    gemv_k<<<4096, 256, 0, stream>>>(fw2, F1, F2, 4096);
    gemv_k<<<1000, 256, 0, stream>>>(fw3, F2, outp, 4096);
}